// Round 12
// baseline (148.407 us; speedup 1.0000x reference)
//
#include <hip/hip_runtime.h>

// RecurrentDecoder: B=8192, T=100, I=30, H=100.
// R12 = R11 + anti-phase stagger + setprio(MFMA).
// 512 blocks x 512 threads (8 waves), B-tile 16. Waves 0-6: one 16-unit tile
// each (wfrag 64 AGPR); wave 7: po-wave (W_d in dead col 112 -> output by MFMA).
// xq in LDS, re-read per step as MFMA C-init. 128 regs/lane -> 2 blocks/CU ->
// 4 waves/SIMD. Co-resident blocks are phase-staggered by half a step so their
// trans/MFMA bursts interleave on the shared SIMD pipes instead of convoying.
// ks-outer MFMA, merged-rcp cell (7 trans/cell), 1 barrier/step, no in-loop VMEM.

#define LOG2E 1.44269504088896340736f

typedef _Float16 f16x8 __attribute__((ext_vector_type(8)));
typedef float    f32x4 __attribute__((ext_vector_type(4)));

__device__ __forceinline__ float rcp_(float x) { return __builtin_amdgcn_rcpf(x); }
__device__ __forceinline__ float exp2_(float x) { return __builtin_amdgcn_exp2f(x); }

#define KS 136   // f16 k-stride (272 B, 16B-aligned, conflict-free proven)

__global__ __launch_bounds__(512, 4) void lstm_kernel(
    const float* __restrict__ x, const float* __restrict__ Wih,
    const float* __restrict__ Whh, const float* __restrict__ bih,
    const float* __restrict__ bhh, const float* __restrict__ Wd,
    const float* __restrict__ bd, float* __restrict__ out)
{
    __shared__ __align__(16) char smem[128 * KS * 2];      // Wstg(34816) U outb(6400)
    __shared__ __align__(16) _Float16 hlds[2][16 * KS];    //  8704 B (dbuf)
    __shared__ __align__(16) float xq_lds[8 * 4 * 64 * 4]; // 32768 B
    // total 76288 B -> 2 blocks/CU

    _Float16* Wstg = (_Float16*)smem;
    float*    outb = (float*)smem;

    const int tid = threadIdx.x;
    const int w   = tid >> 6;      // wave 0..7
    const int l   = tid & 63;
    const int g   = l >> 4;        // 0..3 -> C rows 4g..4g+3
    const int c   = l & 15;        // col within tile / A row
    const int b0  = blockIdx.x * 16;
    const int u   = w * 16 + c;    // unit (identity map; w==7 -> po wave)

    // ---- zero LDS (padding + h(-1)=0; ch 100-127 stay 0 forever) ----
    for (int i = tid; i < 128 * KS / 2; i += 512) ((unsigned*)Wstg)[i] = 0u;
    for (int i = tid; i < 2 * 16 * KS / 2; i += 512) ((unsigned*)&hlds[0][0])[i] = 0u;
    __syncthreads();

    // ---- chunked W staging (one gate per chunk), pre-scaled, identity cols.
    //      Dead col 112 holds W_d (unscaled) -> wave 7's MFMA computes po. ----
    f16x8 wfrag[4][4];   // [s][ks]; wave 7 uses only wfrag[0][*] (= W_d col)
    for (int s = 0; s < 4; ++s) {
        const float sc = (s == 2) ? (-2.0f * LOG2E) : (-LOG2E);
        for (int idx = tid; idx < 10000; idx += 512) {
            int uu = idx / 100, k = idx - uu * 100;
            Wstg[uu * KS + k] = (_Float16)(Whh[(s * 100 + uu) * 100 + k] * sc);
        }
        if (s == 0)
            for (int k = tid; k < 100; k += 512)
                Wstg[112 * KS + k] = (_Float16)Wd[k];
        __syncthreads();
        if (w < 7) {
            #pragma unroll
            for (int ks = 0; ks < 4; ++ks)
                wfrag[s][ks] = *(const f16x8*)&Wstg[u * KS + ks * 32 + g * 8];
        } else if (s == 0) {
            #pragma unroll
            for (int ks = 0; ks < 4; ++ks)
                wfrag[0][ks] = *(const f16x8*)&Wstg[(112 + c) * KS + ks * 32 + g * 8];
        }
        __syncthreads();
    }

    // ---- xq -> LDS (pre-scaled gate pre-acts incl. bias, C-frag coords) ----
    {
        float xq[4][4];
        #pragma unroll
        for (int s = 0; s < 4; ++s)
            #pragma unroll
            for (int r = 0; r < 4; ++r) xq[s][r] = 0.0f;
        if (w < 7 && u < 100) {
            for (int k = 0; k < 30; ++k) {
                float xv[4];
                #pragma unroll
                for (int r = 0; r < 4; ++r) xv[r] = x[(b0 + 4 * g + r) * 30 + k];
                #pragma unroll
                for (int s = 0; s < 4; ++s) {
                    float wv = Wih[(s * 100 + u) * 30 + k];
                    #pragma unroll
                    for (int r = 0; r < 4; ++r) xq[s][r] += xv[r] * wv;
                }
            }
            #pragma unroll
            for (int s = 0; s < 4; ++s) {
                float sc = (s == 2) ? (-2.0f * LOG2E) : (-LOG2E);
                float b  = bih[s * 100 + u] + bhh[s * 100 + u];
                #pragma unroll
                for (int r = 0; r < 4; ++r) xq[s][r] = (xq[s][r] + b) * sc;
            }
        }
        #pragma unroll
        for (int s = 0; s < 4; ++s) {
            f32x4 v = {xq[s][0], xq[s][1], xq[s][2], xq[s][3]};
            *(f32x4*)&xq_lds[(w * 4 + s) * 256 + l * 4] = v;
        }
    }
    const float bdv = bd[0];
    float creg[4] = {0.f, 0.f, 0.f, 0.f};
    __syncthreads();

    // Anti-phase stagger: co-resident blocks (ids differing in bit0 or bit8)
    // offset by ~half a step so their trans/MFMA bursts interleave on the
    // shared SIMD pipes instead of convoying. One-time; identical per-step
    // periods preserve the offset for the whole recurrence.
    if (((blockIdx.x ^ (blockIdx.x >> 8)) & 1) != 0) {
        __builtin_amdgcn_s_sleep(33);   // ~2100 cy
    }

    const int afb = c * KS + g * 8;          // A-frag base (+ks*32)
    const int xqb = w * 1024 + l * 4;        // xq_lds word base (+s*256)
    const int hwb = u;                       // h channel (+row*KS)

    // one LSTM step; P = buffer parity (compile-time), TCUR = step index
#define STEP(P, TCUR)                                                         \
    {                                                                         \
        const _Float16* hr = &hlds[(P)][0];                                   \
        _Float16*       hw = &hlds[(P) ^ 1][0];                               \
        f16x8 af[4];                                                          \
        _Pragma("unroll")                                                     \
        for (int ks = 0; ks < 4; ++ks)                                        \
            af[ks] = *(const f16x8*)&hr[afb + ks * 32];                       \
        if (w < 7) {                                                          \
            f32x4 acc[4];                                                     \
            _Pragma("unroll")                                                 \
            for (int s = 0; s < 4; ++s)                                       \
                acc[s] = *(const f32x4*)&xq_lds[xqb + s * 256];               \
            __builtin_amdgcn_s_setprio(1);                                    \
            _Pragma("unroll")                                                 \
            for (int ks = 0; ks < 4; ++ks)                                    \
                _Pragma("unroll")                                             \
                for (int s = 0; s < 4; ++s)                                   \
                    acc[s] = __builtin_amdgcn_mfma_f32_16x16x32_f16(          \
                            af[ks], wfrag[s][ks], acc[s], 0, 0, 0);           \
            __builtin_amdgcn_s_setprio(0);                                    \
            _Pragma("unroll")                                                 \
            for (int r = 0; r < 4; ++r) {                                     \
                float A  = exp2_(acc[0][r]);                                  \
                float F  = exp2_(acc[1][r]);                                  \
                float G  = exp2_(acc[2][r]);                                  \
                float O  = exp2_(acc[3][r]);                                  \
                float a1 = 1.0f + A, f1 = 1.0f + F;                           \
                float g1 = 1.0f + G, gm = 1.0f - G;                           \
                float ag  = a1 * g1;                                          \
                float num = fmaf(creg[r], ag, gm * f1);                       \
                float cg  = num * rcp_(ag * f1);                              \
                creg[r] = cg;                                                 \
                float C2 = exp2_(cg * (-2.0f * LOG2E));                       \
                float hv = (1.0f - C2) * rcp_((1.0f + O) * (1.0f + C2));      \
                hw[(4 * g + r) * KS + hwb] = (_Float16)hv;                    \
            }                                                                 \
        } else {                                                              \
            f32x4 a = {0.f, 0.f, 0.f, 0.f};                                   \
            __builtin_amdgcn_s_setprio(1);                                    \
            _Pragma("unroll")                                                 \
            for (int ks = 0; ks < 4; ++ks)                                    \
                a = __builtin_amdgcn_mfma_f32_16x16x32_f16(                   \
                        af[ks], wfrag[0][ks], a, 0, 0, 0);                    \
            __builtin_amdgcn_s_setprio(0);                                    \
            if ((TCUR) > 0 && c == 0) {                                       \
                _Pragma("unroll")                                             \
                for (int r = 0; r < 4; ++r)                                   \
                    outb[(4 * g + r) * 100 + (TCUR) - 1] = a[r] + bdv;        \
            }                                                                 \
        }                                                                     \
        __syncthreads();                                                      \
    }

    for (int t2 = 0; t2 < 50; ++t2) {
        STEP(0, 2 * t2);
        STEP(1, 2 * t2 + 1);
    }
#undef STEP

    // epilogue: po(99) from h(99) (in hlds[0]) by wave 7
    if (w == 7) {
        f16x8 af[4];
        #pragma unroll
        for (int ks = 0; ks < 4; ++ks)
            af[ks] = *(const f16x8*)&hlds[0][afb + ks * 32];
        f32x4 a = {0.f, 0.f, 0.f, 0.f};
        #pragma unroll
        for (int ks = 0; ks < 4; ++ks)
            a = __builtin_amdgcn_mfma_f32_16x16x32_f16(af[ks], wfrag[0][ks], a, 0, 0, 0);
        if (c == 0) {
            #pragma unroll
            for (int r = 0; r < 4; ++r)
                outb[(4 * g + r) * 100 + 99] = a[r] + bdv;
        }
    }
    __syncthreads();

    // coalesced vector write of the block's 16x100 outputs
    {
        f32x4*       o4 = (f32x4*)(out + b0 * 100);
        const f32x4* s4 = (const f32x4*)outb;
        for (int i = tid; i < 400; i += 512) o4[i] = s4[i];
    }
}

extern "C" void kernel_launch(void* const* d_in, const int* in_sizes, int n_in,
                              void* d_out, int out_size, void* d_ws, size_t ws_size,
                              hipStream_t stream) {
    (void)in_sizes; (void)n_in; (void)out_size; (void)d_ws; (void)ws_size;
    const float* x   = (const float*)d_in[0];
    const float* Wih = (const float*)d_in[1];
    const float* Whh = (const float*)d_in[2];
    const float* bih = (const float*)d_in[3];
    const float* bhh = (const float*)d_in[4];
    const float* Wd  = (const float*)d_in[5];
    const float* bd  = (const float*)d_in[6];
    lstm_kernel<<<dim3(512), dim3(512), 0, stream>>>(
        x, Wih, Whh, bih, bhh, Wd, bd, (float*)d_out);
}

// Round 13
// 143.041 us; speedup vs baseline: 1.0375x; 1.0375x over previous
//
#include <hip/hip_runtime.h>

// RecurrentDecoder: B=8192, T=100, I=30, H=100.
// R13 = R11 + xq-prefetch-before-barrier (LDS burst halving).
// 512 blocks x 512 threads (8 waves), B-tile 16. Waves 0-6: one 16-unit tile
// each (wfrag 64 AGPR); wave 7: po-wave (W_d in dead col 112 -> output by MFMA).
// xq lives in LDS; its 4 b128 reads for step t+1 are issued PRE-barrier into
// the dead acc registers (acc's last use is the exp2 args), so the post-barrier
// LDS burst is af-only. 128 regs/lane -> 2 blocks/CU -> 4 waves/SIMD.
// ks-outer MFMA, merged-rcp cell (7 trans/cell), 1 barrier/step, no in-loop VMEM.

#define LOG2E 1.44269504088896340736f

typedef _Float16 f16x8 __attribute__((ext_vector_type(8)));
typedef float    f32x4 __attribute__((ext_vector_type(4)));

__device__ __forceinline__ float rcp_(float x) { return __builtin_amdgcn_rcpf(x); }
__device__ __forceinline__ float exp2_(float x) { return __builtin_amdgcn_exp2f(x); }

#define KS 136   // f16 k-stride (272 B = 17*16 B)

__global__ __launch_bounds__(512, 4) void lstm_kernel(
    const float* __restrict__ x, const float* __restrict__ Wih,
    const float* __restrict__ Whh, const float* __restrict__ bih,
    const float* __restrict__ bhh, const float* __restrict__ Wd,
    const float* __restrict__ bd, float* __restrict__ out)
{
    __shared__ __align__(16) char smem[128 * KS * 2];      // Wstg(34816) U outb(6400)
    __shared__ __align__(16) _Float16 hlds[2][16 * KS];    //  8704 B (dbuf)
    __shared__ __align__(16) float xq_lds[8 * 4 * 256];    // 32768 B
    // total 76288 B -> 2 blocks/CU

    _Float16* Wstg = (_Float16*)smem;
    float*    outb = (float*)smem;

    const int tid = threadIdx.x;
    const int w   = tid >> 6;      // wave 0..7
    const int l   = tid & 63;
    const int g   = l >> 4;        // 0..3 -> C rows 4g..4g+3
    const int c   = l & 15;        // col within tile / A row
    const int b0  = blockIdx.x * 16;
    const int u   = w * 16 + c;    // unit (identity map; w==7 -> po wave)

    // ---- zero LDS (padding + h(-1)=0; ch 100-127 stay 0 forever) ----
    for (int i = tid; i < 128 * KS / 2; i += 512) ((unsigned*)Wstg)[i] = 0u;
    for (int i = tid; i < 2 * 16 * KS / 2; i += 512) ((unsigned*)&hlds[0][0])[i] = 0u;
    __syncthreads();

    // ---- chunked W staging (one gate per chunk), pre-scaled, identity cols.
    //      Dead col 112 holds W_d (unscaled) -> wave 7's MFMA computes po. ----
    f16x8 wfrag[4][4];   // [s][ks]; wave 7 uses only wfrag[0][*] (= W_d col)
    for (int s = 0; s < 4; ++s) {
        const float sc = (s == 2) ? (-2.0f * LOG2E) : (-LOG2E);
        for (int idx = tid; idx < 10000; idx += 512) {
            int uu = idx / 100, k = idx - uu * 100;
            Wstg[uu * KS + k] = (_Float16)(Whh[(s * 100 + uu) * 100 + k] * sc);
        }
        if (s == 0)
            for (int k = tid; k < 100; k += 512)
                Wstg[112 * KS + k] = (_Float16)Wd[k];
        __syncthreads();
        if (w < 7) {
            #pragma unroll
            for (int ks = 0; ks < 4; ++ks)
                wfrag[s][ks] = *(const f16x8*)&Wstg[u * KS + ks * 32 + g * 8];
        } else if (s == 0) {
            #pragma unroll
            for (int ks = 0; ks < 4; ++ks)
                wfrag[0][ks] = *(const f16x8*)&Wstg[(112 + c) * KS + ks * 32 + g * 8];
        }
        __syncthreads();
    }

    // ---- xq -> LDS (pre-scaled gate pre-acts incl. bias, C-frag coords) ----
    {
        float xq[4][4];
        #pragma unroll
        for (int s = 0; s < 4; ++s)
            #pragma unroll
            for (int r = 0; r < 4; ++r) xq[s][r] = 0.0f;
        if (w < 7 && u < 100) {
            for (int k = 0; k < 30; ++k) {
                float xv[4];
                #pragma unroll
                for (int r = 0; r < 4; ++r) xv[r] = x[(b0 + 4 * g + r) * 30 + k];
                #pragma unroll
                for (int s = 0; s < 4; ++s) {
                    float wv = Wih[(s * 100 + u) * 30 + k];
                    #pragma unroll
                    for (int r = 0; r < 4; ++r) xq[s][r] += xv[r] * wv;
                }
            }
            #pragma unroll
            for (int s = 0; s < 4; ++s) {
                float sc = (s == 2) ? (-2.0f * LOG2E) : (-LOG2E);
                float b  = bih[s * 100 + u] + bhh[s * 100 + u];
                #pragma unroll
                for (int r = 0; r < 4; ++r) xq[s][r] = (xq[s][r] + b) * sc;
            }
        }
        #pragma unroll
        for (int s = 0; s < 4; ++s) {
            f32x4 v = {xq[s][0], xq[s][1], xq[s][2], xq[s][3]};
            *(f32x4*)&xq_lds[(w * 4 + s) * 256 + l * 4] = v;
        }
    }
    const float bdv = bd[0];
    float creg[4] = {0.f, 0.f, 0.f, 0.f};
    __syncthreads();

    const int afb = c * KS + g * 8;          // A-frag base (+ks*32)
    const int xqb = w * 1024 + l * 4;        // xq_lds word base (+s*256)
    const int hwb = u;                       // h channel (+row*KS)

    // acc persists across steps: holds next step's C-init (xq, prefetched
    // pre-barrier into the dead registers; po-wave: zeros via v_mov).
    f32x4 acc[4];
    if (w < 7) {
        #pragma unroll
        for (int s = 0; s < 4; ++s)
            acc[s] = *(const f32x4*)&xq_lds[xqb + s * 256];
    } else {
        #pragma unroll
        for (int s = 0; s < 4; ++s)
            acc[s] = (f32x4){0.f, 0.f, 0.f, 0.f};
    }
    __syncthreads();

    // one LSTM step; P = buffer parity (compile-time), TCUR = step index
#define STEP(P, TCUR)                                                         \
    {                                                                         \
        const _Float16* hr = &hlds[(P)][0];                                   \
        _Float16*       hw = &hlds[(P) ^ 1][0];                               \
        f16x8 af[4];                                                          \
        _Pragma("unroll")                                                     \
        for (int ks = 0; ks < 4; ++ks)                                        \
            af[ks] = *(const f16x8*)&hr[afb + ks * 32];                       \
        if (w < 7) {                                                          \
            _Pragma("unroll")                                                 \
            for (int ks = 0; ks < 4; ++ks)                                    \
                _Pragma("unroll")                                             \
                for (int s = 0; s < 4; ++s)                                   \
                    acc[s] = __builtin_amdgcn_mfma_f32_16x16x32_f16(          \
                            af[ks], wfrag[s][ks], acc[s], 0, 0, 0);           \
            _Pragma("unroll")                                                 \
            for (int r = 0; r < 4; ++r) {                                     \
                float A  = exp2_(acc[0][r]);                                  \
                float F  = exp2_(acc[1][r]);                                  \
                float G  = exp2_(acc[2][r]);                                  \
                float O  = exp2_(acc[3][r]);                                  \
                float a1 = 1.0f + A, f1 = 1.0f + F;                           \
                float g1 = 1.0f + G, gm = 1.0f - G;                           \
                float ag  = a1 * g1;                                          \
                float num = fmaf(creg[r], ag, gm * f1);                       \
                float cg  = num * rcp_(ag * f1);                              \
                creg[r] = cg;                                                 \
                float C2 = exp2_(cg * (-2.0f * LOG2E));                       \
                float hv = (1.0f - C2) * rcp_((1.0f + O) * (1.0f + C2));      \
                hw[(4 * g + r) * KS + hwb] = (_Float16)hv;                    \
            }                                                                 \
            /* prefetch next step's C-init while the LDS pipe is idle; */     \
            /* drains during barrier wait, halving the post-barrier burst */  \
            _Pragma("unroll")                                                 \
            for (int s = 0; s < 4; ++s)                                       \
                acc[s] = *(const f32x4*)&xq_lds[xqb + s * 256];               \
        } else {                                                              \
            f32x4 a = acc[0];                                                 \
            _Pragma("unroll")                                                 \
            for (int ks = 0; ks < 4; ++ks)                                    \
                a = __builtin_amdgcn_mfma_f32_16x16x32_f16(                   \
                        af[ks], wfrag[0][ks], a, 0, 0, 0);                    \
            if ((TCUR) > 0 && c == 0) {                                       \
                _Pragma("unroll")                                             \
                for (int r = 0; r < 4; ++r)                                   \
                    outb[(4 * g + r) * 100 + (TCUR) - 1] = a[r] + bdv;        \
            }                                                                 \
            acc[0] = (f32x4){0.f, 0.f, 0.f, 0.f};                             \
        }                                                                     \
        __syncthreads();                                                      \
    }

    for (int t2 = 0; t2 < 50; ++t2) {
        STEP(0, 2 * t2);
        STEP(1, 2 * t2 + 1);
    }
#undef STEP

    // epilogue: po(99) from h(99) (in hlds[0]) by wave 7
    if (w == 7) {
        f16x8 af[4];
        #pragma unroll
        for (int ks = 0; ks < 4; ++ks)
            af[ks] = *(const f16x8*)&hlds[0][afb + ks * 32];
        f32x4 a = {0.f, 0.f, 0.f, 0.f};
        #pragma unroll
        for (int ks = 0; ks < 4; ++ks)
            a = __builtin_amdgcn_mfma_f32_16x16x32_f16(af[ks], wfrag[0][ks], a, 0, 0, 0);
        if (c == 0) {
            #pragma unroll
            for (int r = 0; r < 4; ++r)
                outb[(4 * g + r) * 100 + 99] = a[r] + bdv;
        }
    }
    __syncthreads();

    // coalesced vector write of the block's 16x100 outputs
    {
        f32x4*       o4 = (f32x4*)(out + b0 * 100);
        const f32x4* s4 = (const f32x4*)outb;
        for (int i = tid; i < 400; i += 512) o4[i] = s4[i];
    }
}

extern "C" void kernel_launch(void* const* d_in, const int* in_sizes, int n_in,
                              void* d_out, int out_size, void* d_ws, size_t ws_size,
                              hipStream_t stream) {
    (void)in_sizes; (void)n_in; (void)out_size; (void)d_ws; (void)ws_size;
    const float* x   = (const float*)d_in[0];
    const float* Wih = (const float*)d_in[1];
    const float* Whh = (const float*)d_in[2];
    const float* bih = (const float*)d_in[3];
    const float* bhh = (const float*)d_in[4];
    const float* Wd  = (const float*)d_in[5];
    const float* bd  = (const float*)d_in[6];
    lstm_kernel<<<dim3(512), dim3(512), 0, stream>>>(
        x, Wih, Whh, bih, bhh, Wd, bd, (float*)d_out);
}

// Round 14
// 140.098 us; speedup vs baseline: 1.0593x; 1.0210x over previous
//
#include <hip/hip_runtime.h>

// RecurrentDecoder: B=8192, T=100, I=30, H=100.
// R14 = R13 + packed-f32 (v_pk_*) activation arithmetic on row-pairs.
// 512 blocks x 512 threads (8 waves), B-tile 16. Waves 0-6: one 16-unit tile
// each (wfrag 64 AGPR); wave 7: po-wave (W_d in dead col 112 -> output by MFMA).
// xq in LDS, prefetched pre-barrier into dead acc regs. 128 regs/lane ->
// 2 blocks/CU -> 4 waves/SIMD. ks-outer MFMA, merged-rcp cell (7 trans/cell,
// non-trans ops packed 2-wide), 1 barrier/step, no in-loop VMEM.

#define LOG2E 1.44269504088896340736f

typedef _Float16 f16x8 __attribute__((ext_vector_type(8)));
typedef float    f32x4 __attribute__((ext_vector_type(4)));
typedef float    f32x2 __attribute__((ext_vector_type(2)));

__device__ __forceinline__ float rcp_(float x) { return __builtin_amdgcn_rcpf(x); }
__device__ __forceinline__ float exp2_(float x) { return __builtin_amdgcn_exp2f(x); }

#define KS 136   // f16 k-stride (272 B = 17*16 B)

__global__ __launch_bounds__(512, 4) void lstm_kernel(
    const float* __restrict__ x, const float* __restrict__ Wih,
    const float* __restrict__ Whh, const float* __restrict__ bih,
    const float* __restrict__ bhh, const float* __restrict__ Wd,
    const float* __restrict__ bd, float* __restrict__ out)
{
    __shared__ __align__(16) char smem[128 * KS * 2];      // Wstg(34816) U outb(6400)
    __shared__ __align__(16) _Float16 hlds[2][16 * KS];    //  8704 B (dbuf)
    __shared__ __align__(16) float xq_lds[8 * 4 * 256];    // 32768 B
    // total 76288 B -> 2 blocks/CU

    _Float16* Wstg = (_Float16*)smem;
    float*    outb = (float*)smem;

    const int tid = threadIdx.x;
    const int w   = tid >> 6;      // wave 0..7
    const int l   = tid & 63;
    const int g   = l >> 4;        // 0..3 -> C rows 4g..4g+3
    const int c   = l & 15;        // col within tile / A row
    const int b0  = blockIdx.x * 16;
    const int u   = w * 16 + c;    // unit (identity map; w==7 -> po wave)

    // ---- zero LDS (padding + h(-1)=0; ch 100-127 stay 0 forever) ----
    for (int i = tid; i < 128 * KS / 2; i += 512) ((unsigned*)Wstg)[i] = 0u;
    for (int i = tid; i < 2 * 16 * KS / 2; i += 512) ((unsigned*)&hlds[0][0])[i] = 0u;
    __syncthreads();

    // ---- chunked W staging (one gate per chunk), pre-scaled, identity cols.
    //      Dead col 112 holds W_d (unscaled) -> wave 7's MFMA computes po. ----
    f16x8 wfrag[4][4];   // [s][ks]; wave 7 uses only wfrag[0][*] (= W_d col)
    for (int s = 0; s < 4; ++s) {
        const float sc = (s == 2) ? (-2.0f * LOG2E) : (-LOG2E);
        for (int idx = tid; idx < 10000; idx += 512) {
            int uu = idx / 100, k = idx - uu * 100;
            Wstg[uu * KS + k] = (_Float16)(Whh[(s * 100 + uu) * 100 + k] * sc);
        }
        if (s == 0)
            for (int k = tid; k < 100; k += 512)
                Wstg[112 * KS + k] = (_Float16)Wd[k];
        __syncthreads();
        if (w < 7) {
            #pragma unroll
            for (int ks = 0; ks < 4; ++ks)
                wfrag[s][ks] = *(const f16x8*)&Wstg[u * KS + ks * 32 + g * 8];
        } else if (s == 0) {
            #pragma unroll
            for (int ks = 0; ks < 4; ++ks)
                wfrag[0][ks] = *(const f16x8*)&Wstg[(112 + c) * KS + ks * 32 + g * 8];
        }
        __syncthreads();
    }

    // ---- xq -> LDS (pre-scaled gate pre-acts incl. bias, C-frag coords) ----
    {
        float xq[4][4];
        #pragma unroll
        for (int s = 0; s < 4; ++s)
            #pragma unroll
            for (int r = 0; r < 4; ++r) xq[s][r] = 0.0f;
        if (w < 7 && u < 100) {
            for (int k = 0; k < 30; ++k) {
                float xv[4];
                #pragma unroll
                for (int r = 0; r < 4; ++r) xv[r] = x[(b0 + 4 * g + r) * 30 + k];
                #pragma unroll
                for (int s = 0; s < 4; ++s) {
                    float wv = Wih[(s * 100 + u) * 30 + k];
                    #pragma unroll
                    for (int r = 0; r < 4; ++r) xq[s][r] += xv[r] * wv;
                }
            }
            #pragma unroll
            for (int s = 0; s < 4; ++s) {
                float sc = (s == 2) ? (-2.0f * LOG2E) : (-LOG2E);
                float b  = bih[s * 100 + u] + bhh[s * 100 + u];
                #pragma unroll
                for (int r = 0; r < 4; ++r) xq[s][r] = (xq[s][r] + b) * sc;
            }
        }
        #pragma unroll
        for (int s = 0; s < 4; ++s) {
            f32x4 v = {xq[s][0], xq[s][1], xq[s][2], xq[s][3]};
            *(f32x4*)&xq_lds[(w * 4 + s) * 256 + l * 4] = v;
        }
    }
    const float bdv = bd[0];
    // c-state as row-pairs for packed math: creg2[q] = {c[2q], c[2q+1]}
    f32x2 creg2[2] = {{0.f, 0.f}, {0.f, 0.f}};
    __syncthreads();

    const int afb = c * KS + g * 8;          // A-frag base (+ks*32)
    const int xqb = w * 1024 + l * 4;        // xq_lds word base (+s*256)
    const int hwb = u;                       // h channel (+row*KS)

    // acc persists across steps: holds next step's C-init (xq prefetched
    // pre-barrier into the dead registers; po-wave: zeros).
    f32x4 acc[4];
    if (w < 7) {
        #pragma unroll
        for (int s = 0; s < 4; ++s)
            acc[s] = *(const f32x4*)&xq_lds[xqb + s * 256];
    } else {
        #pragma unroll
        for (int s = 0; s < 4; ++s)
            acc[s] = (f32x4){0.f, 0.f, 0.f, 0.f};
    }
    __syncthreads();

    // one LSTM step; P = buffer parity (compile-time), TCUR = step index
#define STEP(P, TCUR)                                                         \
    {                                                                         \
        const _Float16* hr = &hlds[(P)][0];                                   \
        _Float16*       hw = &hlds[(P) ^ 1][0];                               \
        f16x8 af[4];                                                          \
        _Pragma("unroll")                                                     \
        for (int ks = 0; ks < 4; ++ks)                                        \
            af[ks] = *(const f16x8*)&hr[afb + ks * 32];                       \
        if (w < 7) {                                                          \
            _Pragma("unroll")                                                 \
            for (int ks = 0; ks < 4; ++ks)                                    \
                _Pragma("unroll")                                             \
                for (int s = 0; s < 4; ++s)                                   \
                    acc[s] = __builtin_amdgcn_mfma_f32_16x16x32_f16(          \
                            af[ks], wfrag[s][ks], acc[s], 0, 0, 0);           \
            /* packed-f32 activations on row-pairs q=(r0,r1) */               \
            _Pragma("unroll")                                                 \
            for (int q = 0; q < 2; ++q) {                                     \
                f32x2 A2 = {exp2_(acc[0][2 * q]), exp2_(acc[0][2 * q + 1])};  \
                f32x2 F2 = {exp2_(acc[1][2 * q]), exp2_(acc[1][2 * q + 1])};  \
                f32x2 G2 = {exp2_(acc[2][2 * q]), exp2_(acc[2][2 * q + 1])};  \
                f32x2 O2 = {exp2_(acc[3][2 * q]), exp2_(acc[3][2 * q + 1])};  \
                f32x2 a1 = A2 + 1.0f;                                         \
                f32x2 f1 = F2 + 1.0f;                                         \
                f32x2 g1 = G2 + 1.0f;                                         \
                f32x2 gm = 1.0f - G2;                                         \
                f32x2 ag = a1 * g1;                                           \
                f32x2 num = creg2[q] * ag + gm * f1;                          \
                f32x2 den = ag * f1;                                          \
                f32x2 rd = {rcp_(den[0]), rcp_(den[1])};                      \
                f32x2 cg = num * rd;                                          \
                creg2[q] = cg;                                                \
                f32x2 cgk = cg * (-2.0f * LOG2E);                             \
                f32x2 C2 = {exp2_(cgk[0]), exp2_(cgk[1])};                    \
                f32x2 c2m = 1.0f - C2;                                        \
                f32x2 od = (O2 + 1.0f) * (C2 + 1.0f);                         \
                f32x2 ro = {rcp_(od[0]), rcp_(od[1])};                        \
                f32x2 hv = c2m * ro;                                          \
                hw[(4 * g + 2 * q) * KS + hwb]     = (_Float16)hv[0];         \
                hw[(4 * g + 2 * q + 1) * KS + hwb] = (_Float16)hv[1];         \
            }                                                                 \
            /* prefetch next step's C-init while the LDS pipe is idle */      \
            _Pragma("unroll")                                                 \
            for (int s = 0; s < 4; ++s)                                       \
                acc[s] = *(const f32x4*)&xq_lds[xqb + s * 256];               \
        } else {                                                              \
            f32x4 a = acc[0];                                                 \
            _Pragma("unroll")                                                 \
            for (int ks = 0; ks < 4; ++ks)                                    \
                a = __builtin_amdgcn_mfma_f32_16x16x32_f16(                   \
                        af[ks], wfrag[0][ks], a, 0, 0, 0);                    \
            if ((TCUR) > 0 && c == 0) {                                       \
                _Pragma("unroll")                                             \
                for (int r = 0; r < 4; ++r)                                   \
                    outb[(4 * g + r) * 100 + (TCUR) - 1] = a[r] + bdv;        \
            }                                                                 \
            acc[0] = (f32x4){0.f, 0.f, 0.f, 0.f};                             \
        }                                                                     \
        __syncthreads();                                                      \
    }

    for (int t2 = 0; t2 < 50; ++t2) {
        STEP(0, 2 * t2);
        STEP(1, 2 * t2 + 1);
    }
#undef STEP

    // epilogue: po(99) from h(99) (in hlds[0]) by wave 7
    if (w == 7) {
        f16x8 af[4];
        #pragma unroll
        for (int ks = 0; ks < 4; ++ks)
            af[ks] = *(const f16x8*)&hlds[0][afb + ks * 32];
        f32x4 a = {0.f, 0.f, 0.f, 0.f};
        #pragma unroll
        for (int ks = 0; ks < 4; ++ks)
            a = __builtin_amdgcn_mfma_f32_16x16x32_f16(af[ks], wfrag[0][ks], a, 0, 0, 0);
        if (c == 0) {
            #pragma unroll
            for (int r = 0; r < 4; ++r)
                outb[(4 * g + r) * 100 + 99] = a[r] + bdv;
        }
    }
    __syncthreads();

    // coalesced vector write of the block's 16x100 outputs
    {
        f32x4*       o4 = (f32x4*)(out + b0 * 100);
        const f32x4* s4 = (const f32x4*)outb;
        for (int i = tid; i < 400; i += 512) o4[i] = s4[i];
    }
}

extern "C" void kernel_launch(void* const* d_in, const int* in_sizes, int n_in,
                              void* d_out, int out_size, void* d_ws, size_t ws_size,
                              hipStream_t stream) {
    (void)in_sizes; (void)n_in; (void)out_size; (void)d_ws; (void)ws_size;
    const float* x   = (const float*)d_in[0];
    const float* Wih = (const float*)d_in[1];
    const float* Whh = (const float*)d_in[2];
    const float* bih = (const float*)d_in[3];
    const float* bhh = (const float*)d_in[4];
    const float* Wd  = (const float*)d_in[5];
    const float* bd  = (const float*)d_in[6];
    lstm_kernel<<<dim3(512), dim3(512), 0, stream>>>(
        x, Wih, Whh, bih, bhh, Wd, bd, (float*)d_out);
}